// Round 1
// baseline (197.932 us; speedup 1.0000x reference)
//
#include <hip/hip_runtime.h>

#define Bb 4
#define Nn 2048
#define Dd 1024
#define Rr 64
#define LN_EPS 1e-5f

typedef unsigned short u16;
typedef short bf16x8 __attribute__((ext_vector_type(8)));   // 8 bf16 in 4 VGPRs
typedef float f32x4 __attribute__((ext_vector_type(4)));

__device__ __forceinline__ u16 f2bf(float f) {
  unsigned u = __float_as_uint(f);
  u += 0x7FFFu + ((u >> 16) & 1u);   // RNE
  return (u16)(u >> 16);
}

// async global->LDS, 16 B per lane. LDS dest is wave-uniform base + lane*16.
__device__ __forceinline__ void g2l16(u16* l, const u16* g) {
  __builtin_amdgcn_global_load_lds(
      (const __attribute__((address_space(1))) unsigned int*)g,
      (__attribute__((address_space(3))) unsigned int*)l, 16, 0, 0);
}

// raw workgroup barrier that does NOT drain vmcnt (unlike __syncthreads).
// compiler memory fences on both sides stop LDS ops migrating across it.
__device__ __forceinline__ void fence_barrier() {
  asm volatile("" ::: "memory");
  __builtin_amdgcn_s_barrier();
  asm volatile("" ::: "memory");
}

// ---- prep_x: x (B,N,D) f32 -> xt (B,D,N) bf16 (d-major, pv_gemm B-operand) ----
// R6: write side packs 2 consecutive n per lane -> u32 stores (was 2B scalar).
__global__ __launch_bounds__(256) void prep_x(const float* __restrict__ x,
                                              u16* __restrict__ xt) {
  __shared__ float tile[64][65];
  const int b = blockIdx.z;
  const int n0 = blockIdx.x * 64;
  const int d0 = blockIdx.y * 64;
  const int t = threadIdx.x;
  const int c = t & 63, r4 = t >> 6;
#pragma unroll
  for (int rr = 0; rr < 16; rr++) {
    int row = rr * 4 + r4;
    tile[row][c] = x[(size_t)(b * Nn + n0 + row) * Dd + d0 + c];
  }
  __syncthreads();
  const int c2 = t & 31, r8 = t >> 5;
#pragma unroll
  for (int rr = 0; rr < 8; rr++) {
    int dd = rr * 8 + r8;
    unsigned lo = f2bf(tile[2 * c2][dd]);
    unsigned hi = f2bf(tile[2 * c2 + 1][dd]);
    *(unsigned*)&xt[(size_t)(b * Dd + d0 + dd) * Nn + n0 + 2 * c2] = lo | (hi << 16);
  }
}

// ---- prep_small: fuses prep_uv (blocks 0..31) and qscale (blocks 32..2079) ----
__global__ __launch_bounds__(256) void prep_small(const float* __restrict__ U,
    const float* __restrict__ V, const float* __restrict__ mask,
    u16* __restrict__ uvt, float* __restrict__ qs) {
  if (blockIdx.x < 32) {
    __shared__ float tile[64][65];
    const int which = blockIdx.x >> 4;
    const int d0 = (blockIdx.x & 15) * 64;
    const float* src = which ? V : U;
    const int t = threadIdx.x, c = t & 63, r4 = t >> 6;
#pragma unroll
    for (int rr = 0; rr < 16; rr++) {
      int row = rr * 4 + r4;
      tile[row][c] = src[(size_t)(d0 + row) * Rr + c];
    }
    __syncthreads();
#pragma unroll
    for (int rr = 0; rr < 16; rr++) {
      int r = rr * 4 + r4;
      uvt[(size_t)(which * 64 + r) * Dd + d0 + c] = f2bf(tile[c][r]);
    }
  } else {
    const int row = (blockIdx.x - 32) * 4 + (threadIdx.x >> 6);
    const int lane = threadIdx.x & 63;
    float v = mask[(size_t)row * Rr + lane];
#pragma unroll
    for (int off = 32; off; off >>= 1) v += __shfl_xor(v, off);
    if (lane == 0) qs[row] = rsqrtf(fmaxf(v, 1.0f));
  }
}

// ---- proj_qk: Q = (x@U)*mask, K = (x@V)*mask, bf16 out.
// 32 rows x 128 cols/block (grid 256).
__global__ __launch_bounds__(256) void proj_qk(const float* __restrict__ x,
    const float* __restrict__ mask, const u16* __restrict__ uvt,
    u16* __restrict__ Qo, u16* __restrict__ Ko) {
  const int t = threadIdx.x;
  const int w = t >> 6, l = t & 63, quad = l >> 4, l16 = l & 15;
  const int g0 = blockIdx.x * 32;
  f32x4 acc[2][2];
#pragma unroll
  for (int i = 0; i < 2; i++)
#pragma unroll
    for (int j = 0; j < 2; j++) acc[i][j] = (f32x4){0.f, 0.f, 0.f, 0.f};
  for (int k0 = 0; k0 < Dd; k0 += 32) {
    bf16x8 a[2];
#pragma unroll
    for (int mt = 0; mt < 2; mt++) {
      const float4* px = (const float4*)&x[(size_t)(g0 + mt * 16 + l16) * Dd + k0 + quad * 8];
      float4 x0 = px[0], x1 = px[1];
      bf16x8 av;
      av[0] = (short)f2bf(x0.x); av[1] = (short)f2bf(x0.y);
      av[2] = (short)f2bf(x0.z); av[3] = (short)f2bf(x0.w);
      av[4] = (short)f2bf(x1.x); av[5] = (short)f2bf(x1.y);
      av[6] = (short)f2bf(x1.z); av[7] = (short)f2bf(x1.w);
      a[mt] = av;
    }
    bf16x8 bfr[2];
#pragma unroll
    for (int i = 0; i < 2; i++) {
      int col = (w * 2 + i) * 16 + l16;
      bfr[i] = *(const bf16x8*)&uvt[(size_t)col * Dd + k0 + quad * 8];
    }
#pragma unroll
    for (int mt = 0; mt < 2; mt++)
#pragma unroll
      for (int i = 0; i < 2; i++)
        acc[mt][i] = __builtin_amdgcn_mfma_f32_16x16x32_bf16(a[mt], bfr[i], acc[mt][i], 0, 0, 0);
  }
#pragma unroll
  for (int mt = 0; mt < 2; mt++)
#pragma unroll
    for (int i = 0; i < 2; i++) {
      int col = (w * 2 + i) * 16 + l16;
      int r_ = col & 63;
#pragma unroll
      for (int r = 0; r < 4; r++) {
        int row = g0 + mt * 16 + quad * 4 + r;
        float v = acc[mt][i][r] * mask[(size_t)row * Rr + r_];
        u16 bv = f2bf(v);
        if (col < 64) Qo[(size_t)row * Rr + r_] = bv;
        else          Ko[(size_t)row * Rr + r_] = bv;
      }
    }
}

// ---- score_softmax: block = 32 q-rows x ALL 2048 keys, 8 waves.
// Whole-row softmax once per block. Writes P = exp(v - rowmax) bf16
// (unnormalized) and linv = 1/rowsum.
__global__ __launch_bounds__(512, 2) void score_softmax(
    const u16* __restrict__ Qm, const u16* __restrict__ Km,
    const float* __restrict__ qs, u16* __restrict__ Pw,
    float* __restrict__ linv_g) {
  __shared__ float red[32][8];
  __shared__ float mfin[32];
  const int t = threadIdx.x;
  const int w = t >> 6, l = t & 63, quad = l >> 4, l16 = l & 15;
  const int id = blockIdx.x;
  const int xcd = id & 7;
  const int b = xcd >> 1;
  const int q0 = (((id >> 3) << 1) | (xcd & 1)) * 32;
  bf16x8 qf[2][2];
#pragma unroll
  for (int mt = 0; mt < 2; mt++)
#pragma unroll
    for (int ks = 0; ks < 2; ks++)
      qf[mt][ks] = *(const bf16x8*)&Qm[(size_t)(b * Nn + q0 + mt * 16 + l16) * Rr + ks * 32 + quad * 8];
  f32x4 acc[2][16];
#pragma unroll
  for (int mt = 0; mt < 2; mt++)
#pragma unroll
    for (int nt = 0; nt < 16; nt++) acc[mt][nt] = (f32x4){0.f, 0.f, 0.f, 0.f};
#pragma unroll
  for (int nt = 0; nt < 16; nt++) {
#pragma unroll
    for (int ks = 0; ks < 2; ks++) {
      bf16x8 kf = *(const bf16x8*)&Km[(size_t)(b * Nn + w * 256 + nt * 16 + l16) * Rr + ks * 32 + quad * 8];
#pragma unroll
      for (int mt = 0; mt < 2; mt++)
        acc[mt][nt] = __builtin_amdgcn_mfma_f32_16x16x32_bf16(qf[mt][ks], kf, acc[mt][nt], 0, 0, 0);
    }
  }
  float sc[2][4];
#pragma unroll
  for (int mt = 0; mt < 2; mt++)
#pragma unroll
    for (int r = 0; r < 4; r++)
      sc[mt][r] = qs[(size_t)b * Nn + q0 + mt * 16 + quad * 4 + r];
#pragma unroll
  for (int mt = 0; mt < 2; mt++)
#pragma unroll
    for (int nt = 0; nt < 16; nt++)
#pragma unroll
      for (int r = 0; r < 4; r++) acc[mt][nt][r] *= sc[mt][r];
  float vmax[2][4];
#pragma unroll
  for (int mt = 0; mt < 2; mt++)
#pragma unroll
    for (int r = 0; r < 4; r++) {
      float m = -1e30f;
#pragma unroll
      for (int nt = 0; nt < 16; nt++) m = fmaxf(m, acc[mt][nt][r]);
#pragma unroll
      for (int off = 1; off < 16; off <<= 1) m = fmaxf(m, __shfl_xor(m, off));
      vmax[mt][r] = m;
    }
  if (l16 == 0) {
#pragma unroll
    for (int mt = 0; mt < 2; mt++)
#pragma unroll
      for (int r = 0; r < 4; r++) red[mt * 16 + quad * 4 + r][w] = vmax[mt][r];
  }
  __syncthreads();
  if (t < 32) {
    float m = -1e30f;
#pragma unroll
    for (int i = 0; i < 8; i++) m = fmaxf(m, red[t][i]);
    mfin[t] = m;
  }
  __syncthreads();
  float rowm[2][4], vsum[2][4];
#pragma unroll
  for (int mt = 0; mt < 2; mt++)
#pragma unroll
    for (int r = 0; r < 4; r++) {
      rowm[mt][r] = mfin[mt * 16 + quad * 4 + r];
      vsum[mt][r] = 0.f;
    }
#pragma unroll
  for (int mt = 0; mt < 2; mt++)
#pragma unroll
    for (int nt = 0; nt < 16; nt++)
#pragma unroll
      for (int r = 0; r < 4; r++) {
        float p = __expf(acc[mt][nt][r] - rowm[mt][r]);
        acc[mt][nt][r] = p;
        vsum[mt][r] += p;
      }
#pragma unroll
  for (int mt = 0; mt < 2; mt++)
#pragma unroll
    for (int r = 0; r < 4; r++) {
#pragma unroll
      for (int off = 1; off < 16; off <<= 1) vsum[mt][r] += __shfl_xor(vsum[mt][r], off);
    }
  __syncthreads();   // red[] reuse
  if (l16 == 0) {
#pragma unroll
    for (int mt = 0; mt < 2; mt++)
#pragma unroll
      for (int r = 0; r < 4; r++) red[mt * 16 + quad * 4 + r][w] = vsum[mt][r];
  }
  __syncthreads();
  if (t < 32) {
    float s = 0.f;
#pragma unroll
    for (int i = 0; i < 8; i++) s += red[t][i];
    linv_g[(size_t)b * Nn + q0 + t] = 1.f / s;
  }
#pragma unroll
  for (int mt = 0; mt < 2; mt++)
#pragma unroll
    for (int nt = 0; nt < 16; nt++) {
      const size_t base = ((size_t)(b * Nn + q0 + mt * 16 + quad * 4)) * Nn + w * 256 + nt * 16 + l16;
#pragma unroll
      for (int r = 0; r < 4; r++)
        Pw[base + (size_t)r * Nn] = f2bf(acc[mt][nt][r]);
    }
}

// ---- pv_gemm v2: delta = P @ X. 256x128 tile, BK=64, 512 thr (8 waves 4Mx2N).
// T3+T4: 3-deep LDS pipeline (144 KB), 2-tile lookahead, counted vmcnt(6) at
// each K-tile top (never 0 in steady state), loads interleaved across 4 phases,
// raw s_barrier (no vmcnt drain). T5: setprio(1) around each 8-MFMA cluster.
// XOR k-chunk swizzle identical to R5 (measured 0 LDS bank conflicts):
// staging lane fetches global chunk (l&7)^(l>>3) so LDS[R][c] = global chunk
// c^(R&7); frag read slot = (ks*4+quad)^(l16&7).
__global__ __launch_bounds__(512, 2) void pv_gemm(
    const u16* __restrict__ Pw, const u16* __restrict__ xt,
    const float* __restrict__ x, const float* __restrict__ linv_g,
    float* __restrict__ y) {
  __shared__ u16 As[3][256 * 64];   // 96 KB  [row m][swizzled k-slot]
  __shared__ u16 Bs[3][128 * 64];   // 48 KB  [col d][swizzled k-slot]
  const int t = threadIdx.x;
  const int w = t >> 6, l = t & 63, quad = l >> 4, l16 = l & 15;
  const int id = blockIdx.x;
  const int xcd = id & 7;
  const int b = xcd >> 1;
  const int nh = xcd & 1;
  const int rest = id >> 3;                    // 0..31
  const int m0 = (rest >> 2) * 256;            // 8 m-tiles
  const int n0 = (nh * 4 + (rest & 3)) * 128;  // 8 n-tiles, 4 per XCD-half
  const int lrow = l >> 3;                     // 0..7
  const int skoff = ((l & 7) ^ lrow) * 8;      // swizzled global k-chunk
  const size_t gA = (size_t)(b * Nn + m0 + w * 8 + lrow) * Nn + skoff;
  const size_t gB = (size_t)(b * Dd + n0 + w * 8 + lrow) * Nn + skoff;
  const int wm = w >> 1, wn = w & 1;           // 4M x 2N wave grid
  const int sw = l16 & 7;
  f32x4 acc[4][4];
#pragma unroll
  for (int i = 0; i < 4; i++)
#pragma unroll
    for (int j = 0; j < 4; j++) acc[i][j] = (f32x4){0.f, 0.f, 0.f, 0.f};

#define STA(bf, j, k0) g2l16(&As[bf][((j) * 64 + w * 8) * 64], \
                             &Pw[gA + (size_t)(j) * 64 * Nn + (size_t)(k0)])
#define STB(bf, j, k0) g2l16(&Bs[bf][((j) * 64 + w * 8) * 64], \
                             &xt[gB + (size_t)(j) * 64 * Nn + (size_t)(k0)])

  // prologue: tiles 0,1 -> bufs 0,1 (6 loads each per wave; 12 in flight)
#pragma unroll
  for (int j = 0; j < 4; j++) STA(0, j, 0);
  STB(0, 0, 0);
  STB(0, 1, 0);
#pragma unroll
  for (int j = 0; j < 4; j++) STA(1, j, 64);
  STB(1, 0, 64);
  STB(1, 1, 64);

  int bufc = 0;
  for (int kt = 0; kt < Nn / 64; kt++) {
    // wait for tile kt (issued 2 iterations ago); tile kt+1's 6 stay in flight
    if (kt == Nn / 64 - 1) asm volatile("s_waitcnt vmcnt(0)" ::: "memory");
    else                   asm volatile("s_waitcnt vmcnt(6)" ::: "memory");
    __builtin_amdgcn_s_barrier();
    asm volatile("" ::: "memory");
    const int bufs = (bufc == 0) ? 2 : bufc - 1;   // == (kt+2)%3, freed last iter
    const int k2 = (kt + 2) * 64;
    const bool st = kt < Nn / 64 - 2;
    bf16x8 af[4], bfr[4];
    // ---- phase 0: ks=0, nt 0-1 ----
    {
      const int slot = (quad ^ sw) * 8;
#pragma unroll
      for (int mt = 0; mt < 4; mt++)
        af[mt] = *(const bf16x8*)&As[bufc][(wm * 64 + mt * 16 + l16) * 64 + slot];
#pragma unroll
      for (int nt = 0; nt < 2; nt++)
        bfr[nt] = *(const bf16x8*)&Bs[bufc][(wn * 64 + nt * 16 + l16) * 64 + slot];
      if (st) { STA(bufs, 0, k2); STA(bufs, 1, k2); }
      __builtin_amdgcn_s_setprio(1);
#pragma unroll
      for (int mt = 0; mt < 4; mt++)
#pragma unroll
        for (int nt = 0; nt < 2; nt++)
          acc[mt][nt] = __builtin_amdgcn_mfma_f32_16x16x32_bf16(af[mt], bfr[nt], acc[mt][nt], 0, 0, 0);
      __builtin_amdgcn_s_setprio(0);
      fence_barrier();
    }
    // ---- phase 1: ks=0, nt 2-3 ----
    {
      const int slot = (quad ^ sw) * 8;
#pragma unroll
      for (int nt = 2; nt < 4; nt++)
        bfr[nt] = *(const bf16x8*)&Bs[bufc][(wn * 64 + nt * 16 + l16) * 64 + slot];
      if (st) { STA(bufs, 2, k2); STA(bufs, 3, k2); }
      __builtin_amdgcn_s_setprio(1);
#pragma unroll
      for (int mt = 0; mt < 4; mt++)
#pragma unroll
        for (int nt = 2; nt < 4; nt++)
          acc[mt][nt] = __builtin_amdgcn_mfma_f32_16x16x32_bf16(af[mt], bfr[nt], acc[mt][nt], 0, 0, 0);
      __builtin_amdgcn_s_setprio(0);
      fence_barrier();
    }
    // ---- phase 2: ks=1, nt 0-1 ----
    {
      const int slot = ((4 + quad) ^ sw) * 8;
#pragma unroll
      for (int mt = 0; mt < 4; mt++)
        af[mt] = *(const bf16x8*)&As[bufc][(wm * 64 + mt * 16 + l16) * 64 + slot];
#pragma unroll
      for (int nt = 0; nt < 2; nt++)
        bfr[nt] = *(const bf16x8*)&Bs[bufc][(wn * 64 + nt * 16 + l16) * 64 + slot];
      if (st) STB(bufs, 0, k2);
      __builtin_amdgcn_s_setprio(1);
#pragma unroll
      for (int mt = 0; mt < 4; mt++)
#pragma unroll
        for (int nt = 0; nt < 2; nt++)
          acc[mt][nt] = __builtin_amdgcn_mfma_f32_16x16x32_bf16(af[mt], bfr[nt], acc[mt][nt], 0, 0, 0);
      __builtin_amdgcn_s_setprio(0);
      fence_barrier();
    }
    // ---- phase 3: ks=1, nt 2-3 (no trailing barrier: top-of-loop covers) ----
    {
      const int slot = ((4 + quad) ^ sw) * 8;
#pragma unroll
      for (int nt = 2; nt < 4; nt++)
        bfr[nt] = *(const bf16x8*)&Bs[bufc][(wn * 64 + nt * 16 + l16) * 64 + slot];
      if (st) STB(bufs, 1, k2);
      __builtin_amdgcn_s_setprio(1);
#pragma unroll
      for (int mt = 0; mt < 4; mt++)
#pragma unroll
        for (int nt = 2; nt < 4; nt++)
          acc[mt][nt] = __builtin_amdgcn_mfma_f32_16x16x32_bf16(af[mt], bfr[nt], acc[mt][nt], 0, 0, 0);
      __builtin_amdgcn_s_setprio(0);
    }
    bufc = (bufc == 2) ? 0 : bufc + 1;
  }
#undef STA
#undef STB
  // ---- epilogue: y = x + linv[m] * delta ----
  float li[4][4];
#pragma unroll
  for (int mt = 0; mt < 4; mt++)
#pragma unroll
    for (int r = 0; r < 4; r++)
      li[mt][r] = linv_g[(size_t)b * Nn + m0 + wm * 64 + mt * 16 + quad * 4 + r];
#pragma unroll
  for (int mt = 0; mt < 4; mt++)
#pragma unroll
    for (int nt = 0; nt < 4; nt++) {
      const int nn = n0 + wn * 64 + nt * 16 + l16;
#pragma unroll
      for (int r = 0; r < 4; r++) {
        const int m = m0 + wm * 64 + mt * 16 + quad * 4 + r;
        const size_t off = ((size_t)(b * Nn + m)) * Dd + nn;
        y[off] = x[off] + li[mt][r] * acc[mt][nt][r];
      }
    }
}

// ---- ln_k: in-place row-wise LayerNorm over d_out. 1 block (256 thr) per row ----
__global__ __launch_bounds__(256) void ln_k(float* __restrict__ y,
    const float* __restrict__ gamma, const float* __restrict__ beta) {
  __shared__ float rs[4], rq[4];
  const int row = blockIdx.x;
  const int t = threadIdx.x;
  float* p = y + (size_t)row * Dd;
  float4 v = ((const float4*)p)[t];
  float s = v.x + v.y + v.z + v.w;
  float q = v.x * v.x + v.y * v.y + v.z * v.z + v.w * v.w;
#pragma unroll
  for (int off = 32; off; off >>= 1) {
    s += __shfl_xor(s, off);
    q += __shfl_xor(q, off);
  }
  if ((t & 63) == 0) { rs[t >> 6] = s; rq[t >> 6] = q; }
  __syncthreads();
  float S = rs[0] + rs[1] + rs[2] + rs[3];
  float Q2 = rq[0] + rq[1] + rq[2] + rq[3];
  float mu = S * (1.f / Dd);
  float var = Q2 * (1.f / Dd) - mu * mu;
  float rstd = rsqrtf(var + LN_EPS);
  float4 g = ((const float4*)gamma)[t];
  float4 be = ((const float4*)beta)[t];
  v.x = (v.x - mu) * rstd * g.x + be.x;
  v.y = (v.y - mu) * rstd * g.y + be.y;
  v.z = (v.z - mu) * rstd * g.z + be.z;
  v.w = (v.w - mu) * rstd * g.w + be.w;
  ((float4*)p)[t] = v;
}

extern "C" void kernel_launch(void* const* d_in, const int* in_sizes, int n_in,
                              void* d_out, int out_size, void* d_ws, size_t ws_size,
                              hipStream_t stream) {
  const float* x     = (const float*)d_in[0];
  const float* mask  = (const float*)d_in[1];
  const float* U     = (const float*)d_in[2];
  const float* V     = (const float*)d_in[3];
  const float* gamma = (const float*)d_in[4];
  const float* beta  = (const float*)d_in[5];
  float* out = (float*)d_out;
  char* ws = (char*)d_ws;
  // workspace layout (51 MB total)
  u16*   xt   = (u16*)ws;                                        // 16 MB (B,D,N) bf16
  u16*   Qw   = (u16*)(ws + (size_t)(16 << 20));                 // 1 MB
  u16*   Kw   = (u16*)(ws + (size_t)(17 << 20));                 // 1 MB
  u16*   uvt  = (u16*)(ws + (size_t)(18 << 20));                 // 256 KB
  float* qsb  = (float*)(ws + (size_t)(18 << 20) + (256 << 10)); // 32 KB
  float* linv = (float*)(ws + (size_t)(18 << 20) + (288 << 10)); // 32 KB
  u16*   Pw   = (u16*)(ws + (size_t)(19 << 20));                 // 32 MB (B,N,N) bf16

  prep_x       <<<dim3(Nn / 64, Dd / 64, Bb), 256, 0, stream>>>(x, xt);
  prep_small   <<<32 + (Bb * Nn) / 4, 256, 0, stream>>>(U, V, mask, uvt, qsb);
  proj_qk      <<<(Bb * Nn) / 32, 256, 0, stream>>>(x, mask, uvt, Qw, Kw);
  score_softmax<<<Bb * (Nn / 32), 512, 0, stream>>>(Qw, Kw, qsb, Pw, linv);
  pv_gemm      <<<Bb * (Nn / 256) * (Dd / 128), 512, 0, stream>>>(Pw, xt, x, linv, out);
  ln_k         <<<Bb * Nn, 256, 0, stream>>>(out, gamma, beta);
}

// Round 2
// 189.830 us; speedup vs baseline: 1.0427x; 1.0427x over previous
//
#include <hip/hip_runtime.h>

#define Bb 4
#define Nn 2048
#define Dd 1024
#define Rr 64
#define LN_EPS 1e-5f

typedef unsigned short u16;
typedef short bf16x8 __attribute__((ext_vector_type(8)));   // 8 bf16 in 4 VGPRs
typedef float f32x4 __attribute__((ext_vector_type(4)));

__device__ __forceinline__ u16 f2bf(float f) {
  unsigned u = __float_as_uint(f);
  u += 0x7FFFu + ((u >> 16) & 1u);   // RNE
  return (u16)(u >> 16);
}

// async global->LDS, 16 B per lane. LDS dest is wave-uniform base + lane*16.
__device__ __forceinline__ void g2l16(u16* l, const u16* g) {
  __builtin_amdgcn_global_load_lds(
      (const __attribute__((address_space(1))) unsigned int*)g,
      (__attribute__((address_space(3))) unsigned int*)l, 16, 0, 0);
}

// ---- prep_x: x (B,N,D) f32 -> xt (B,D,N) bf16 (d-major, pv_gemm B-operand) ----
__global__ __launch_bounds__(256) void prep_x(const float* __restrict__ x,
                                              u16* __restrict__ xt) {
  __shared__ float tile[64][65];
  const int b = blockIdx.z;
  const int n0 = blockIdx.x * 64;
  const int d0 = blockIdx.y * 64;
  const int t = threadIdx.x;
  const int c = t & 63, r4 = t >> 6;
#pragma unroll
  for (int rr = 0; rr < 16; rr++) {
    int row = rr * 4 + r4;
    tile[row][c] = x[(size_t)(b * Nn + n0 + row) * Dd + d0 + c];
  }
  __syncthreads();
#pragma unroll
  for (int rr = 0; rr < 16; rr++) {
    int dd = rr * 4 + r4;
    xt[(size_t)(b * Dd + d0 + dd) * Nn + n0 + c] = f2bf(tile[c][dd]);
  }
}

// ---- prep_small: fuses prep_uv (blocks 0..31) and qscale (blocks 32..2079) ----
__global__ __launch_bounds__(256) void prep_small(const float* __restrict__ U,
    const float* __restrict__ V, const float* __restrict__ mask,
    u16* __restrict__ uvt, float* __restrict__ qs) {
  if (blockIdx.x < 32) {
    __shared__ float tile[64][65];
    const int which = blockIdx.x >> 4;
    const int d0 = (blockIdx.x & 15) * 64;
    const float* src = which ? V : U;
    const int t = threadIdx.x, c = t & 63, r4 = t >> 6;
#pragma unroll
    for (int rr = 0; rr < 16; rr++) {
      int row = rr * 4 + r4;
      tile[row][c] = src[(size_t)(d0 + row) * Rr + c];
    }
    __syncthreads();
#pragma unroll
    for (int rr = 0; rr < 16; rr++) {
      int r = rr * 4 + r4;
      uvt[(size_t)(which * 64 + r) * Dd + d0 + c] = f2bf(tile[c][r]);
    }
  } else {
    const int row = (blockIdx.x - 32) * 4 + (threadIdx.x >> 6);
    const int lane = threadIdx.x & 63;
    float v = mask[(size_t)row * Rr + lane];
#pragma unroll
    for (int off = 32; off; off >>= 1) v += __shfl_xor(v, off);
    if (lane == 0) qs[row] = rsqrtf(fmaxf(v, 1.0f));
  }
}

// ---- proj_qk: Q = (x@U)*mask, K = (x@V)*mask, bf16 out.
// 32 rows x 128 cols/block (grid 256).
__global__ __launch_bounds__(256) void proj_qk(const float* __restrict__ x,
    const float* __restrict__ mask, const u16* __restrict__ uvt,
    u16* __restrict__ Qo, u16* __restrict__ Ko) {
  const int t = threadIdx.x;
  const int w = t >> 6, l = t & 63, quad = l >> 4, l16 = l & 15;
  const int g0 = blockIdx.x * 32;
  f32x4 acc[2][2];
#pragma unroll
  for (int i = 0; i < 2; i++)
#pragma unroll
    for (int j = 0; j < 2; j++) acc[i][j] = (f32x4){0.f, 0.f, 0.f, 0.f};
  for (int k0 = 0; k0 < Dd; k0 += 32) {
    bf16x8 a[2];
#pragma unroll
    for (int mt = 0; mt < 2; mt++) {
      const float4* px = (const float4*)&x[(size_t)(g0 + mt * 16 + l16) * Dd + k0 + quad * 8];
      float4 x0 = px[0], x1 = px[1];
      bf16x8 av;
      av[0] = (short)f2bf(x0.x); av[1] = (short)f2bf(x0.y);
      av[2] = (short)f2bf(x0.z); av[3] = (short)f2bf(x0.w);
      av[4] = (short)f2bf(x1.x); av[5] = (short)f2bf(x1.y);
      av[6] = (short)f2bf(x1.z); av[7] = (short)f2bf(x1.w);
      a[mt] = av;
    }
    bf16x8 bfr[2];
#pragma unroll
    for (int i = 0; i < 2; i++) {
      int col = (w * 2 + i) * 16 + l16;
      bfr[i] = *(const bf16x8*)&uvt[(size_t)col * Dd + k0 + quad * 8];
    }
#pragma unroll
    for (int mt = 0; mt < 2; mt++)
#pragma unroll
      for (int i = 0; i < 2; i++)
        acc[mt][i] = __builtin_amdgcn_mfma_f32_16x16x32_bf16(a[mt], bfr[i], acc[mt][i], 0, 0, 0);
  }
#pragma unroll
  for (int mt = 0; mt < 2; mt++)
#pragma unroll
    for (int i = 0; i < 2; i++) {
      int col = (w * 2 + i) * 16 + l16;
      int r_ = col & 63;
#pragma unroll
      for (int r = 0; r < 4; r++) {
        int row = g0 + mt * 16 + quad * 4 + r;
        float v = acc[mt][i][r] * mask[(size_t)row * Rr + r_];
        u16 bv = f2bf(v);
        if (col < 64) Qo[(size_t)row * Rr + r_] = bv;
        else          Ko[(size_t)row * Rr + r_] = bv;
      }
    }
}

// ---- score_softmax: block = 32 q-rows x ALL 2048 keys, 8 waves.
// Whole-row softmax once per block. Writes P = exp(v - rowmax) bf16
// (unnormalized) and linv = 1/rowsum.
__global__ __launch_bounds__(512, 2) void score_softmax(
    const u16* __restrict__ Qm, const u16* __restrict__ Km,
    const float* __restrict__ qs, u16* __restrict__ Pw,
    float* __restrict__ linv_g) {
  __shared__ float red[32][8];
  __shared__ float mfin[32];
  const int t = threadIdx.x;
  const int w = t >> 6, l = t & 63, quad = l >> 4, l16 = l & 15;
  const int id = blockIdx.x;
  const int xcd = id & 7;
  const int b = xcd >> 1;
  const int q0 = (((id >> 3) << 1) | (xcd & 1)) * 32;
  bf16x8 qf[2][2];
#pragma unroll
  for (int mt = 0; mt < 2; mt++)
#pragma unroll
    for (int ks = 0; ks < 2; ks++)
      qf[mt][ks] = *(const bf16x8*)&Qm[(size_t)(b * Nn + q0 + mt * 16 + l16) * Rr + ks * 32 + quad * 8];
  f32x4 acc[2][16];
#pragma unroll
  for (int mt = 0; mt < 2; mt++)
#pragma unroll
    for (int nt = 0; nt < 16; nt++) acc[mt][nt] = (f32x4){0.f, 0.f, 0.f, 0.f};
#pragma unroll
  for (int nt = 0; nt < 16; nt++) {
#pragma unroll
    for (int ks = 0; ks < 2; ks++) {
      bf16x8 kf = *(const bf16x8*)&Km[(size_t)(b * Nn + w * 256 + nt * 16 + l16) * Rr + ks * 32 + quad * 8];
#pragma unroll
      for (int mt = 0; mt < 2; mt++)
        acc[mt][nt] = __builtin_amdgcn_mfma_f32_16x16x32_bf16(qf[mt][ks], kf, acc[mt][nt], 0, 0, 0);
    }
  }
  float sc[2][4];
#pragma unroll
  for (int mt = 0; mt < 2; mt++)
#pragma unroll
    for (int r = 0; r < 4; r++)
      sc[mt][r] = qs[(size_t)b * Nn + q0 + mt * 16 + quad * 4 + r];
#pragma unroll
  for (int mt = 0; mt < 2; mt++)
#pragma unroll
    for (int nt = 0; nt < 16; nt++)
#pragma unroll
      for (int r = 0; r < 4; r++) acc[mt][nt][r] *= sc[mt][r];
  float vmax[2][4];
#pragma unroll
  for (int mt = 0; mt < 2; mt++)
#pragma unroll
    for (int r = 0; r < 4; r++) {
      float m = -1e30f;
#pragma unroll
      for (int nt = 0; nt < 16; nt++) m = fmaxf(m, acc[mt][nt][r]);
#pragma unroll
      for (int off = 1; off < 16; off <<= 1) m = fmaxf(m, __shfl_xor(m, off));
      vmax[mt][r] = m;
    }
  if (l16 == 0) {
#pragma unroll
    for (int mt = 0; mt < 2; mt++)
#pragma unroll
      for (int r = 0; r < 4; r++) red[mt * 16 + quad * 4 + r][w] = vmax[mt][r];
  }
  __syncthreads();
  if (t < 32) {
    float m = -1e30f;
#pragma unroll
    for (int i = 0; i < 8; i++) m = fmaxf(m, red[t][i]);
    mfin[t] = m;
  }
  __syncthreads();
  float rowm[2][4], vsum[2][4];
#pragma unroll
  for (int mt = 0; mt < 2; mt++)
#pragma unroll
    for (int r = 0; r < 4; r++) {
      rowm[mt][r] = mfin[mt * 16 + quad * 4 + r];
      vsum[mt][r] = 0.f;
    }
#pragma unroll
  for (int mt = 0; mt < 2; mt++)
#pragma unroll
    for (int nt = 0; nt < 16; nt++)
#pragma unroll
      for (int r = 0; r < 4; r++) {
        float p = __expf(acc[mt][nt][r] - rowm[mt][r]);
        acc[mt][nt][r] = p;
        vsum[mt][r] += p;
      }
#pragma unroll
  for (int mt = 0; mt < 2; mt++)
#pragma unroll
    for (int r = 0; r < 4; r++) {
#pragma unroll
      for (int off = 1; off < 16; off <<= 1) vsum[mt][r] += __shfl_xor(vsum[mt][r], off);
    }
  __syncthreads();   // red[] reuse
  if (l16 == 0) {
#pragma unroll
    for (int mt = 0; mt < 2; mt++)
#pragma unroll
      for (int r = 0; r < 4; r++) red[mt * 16 + quad * 4 + r][w] = vsum[mt][r];
  }
  __syncthreads();
  if (t < 32) {
    float s = 0.f;
#pragma unroll
    for (int i = 0; i < 8; i++) s += red[t][i];
    linv_g[(size_t)b * Nn + q0 + t] = 1.f / s;
  }
#pragma unroll
  for (int mt = 0; mt < 2; mt++)
#pragma unroll
    for (int nt = 0; nt < 16; nt++) {
      const size_t base = ((size_t)(b * Nn + q0 + mt * 16 + quad * 4)) * Nn + w * 256 + nt * 16 + l16;
#pragma unroll
      for (int r = 0; r < 4; r++)
        Pw[base + (size_t)r * Nn] = f2bf(acc[mt][nt][r]);
    }
}

// ---- pv_gemm: delta = P @ X. 128x128 tile, BK=64 — R5's proven 2-barrier
// structure (stage -> sync -> compute), UNCHANGED sync/traffic. R7: 8 waves
// (512 thr, 2M x 4N wave grid, per-wave 64x32, acc[4][2]) instead of 4.
// Same 32 KB LDS, same grid 512, 2 blocks/CU -> 16 waves/CU = 4 waves/SIMD
// (was 2): pure latency-hiding occupancy gain. XOR k-chunk swizzle identical
// to R5 (measured 0 LDS bank conflicts): staging lane fetches global chunk
// (l&7)^lrow so LDS[row][c] = global chunk c^(row&7); frag read slot
// = (ks*4+quad)^(l16&7).
__global__ __launch_bounds__(512, 4) void pv_gemm(
    const u16* __restrict__ Pw, const u16* __restrict__ xt,
    const float* __restrict__ x, const float* __restrict__ linv_g,
    float* __restrict__ y) {
  __shared__ u16 As[128 * 64];   // [row m][k-slot] swizzled
  __shared__ u16 Bs[128 * 64];   // [col n(d)][k-slot] swizzled
  const int t = threadIdx.x;
  const int w = t >> 6, l = t & 63, quad = l >> 4, l16 = l & 15;
  const int id = blockIdx.x;
  const int xcd = id & 7;
  const int b = xcd >> 1;
  const int nh = xcd & 1;
  const int rest = id >> 3;             // 0..63
  const int m0 = (rest & 15) * 128;     // 16 m-tiles
  const int n0 = (nh * 4 + (rest >> 4)) * 128;  // 8 n-tiles
  const int lrow = l >> 3;              // 0..7
  const int srow = w * 8 + lrow;        // staging row 0..63 (+64 second round)
  const int skoff = ((l & 7) ^ lrow) * 8;  // swizzled global k-chunk
  const int wm = w >> 2, wn = w & 3;    // 2M x 4N wave grid
  const int sw = l16 & 7;
  f32x4 acc[4][2];
#pragma unroll
  for (int i = 0; i < 4; i++)
#pragma unroll
    for (int j = 0; j < 2; j++) acc[i][j] = (f32x4){0.f, 0.f, 0.f, 0.f};
  for (int k0 = 0; k0 < Nn; k0 += 64) {
    __syncthreads();   // previous compute done before LDS overwrite
    g2l16(&As[(w * 8) * 64],
          &Pw[((size_t)(b * Nn + m0 + srow)) * Nn + k0 + skoff]);
    g2l16(&As[(64 + w * 8) * 64],
          &Pw[((size_t)(b * Nn + m0 + 64 + srow)) * Nn + k0 + skoff]);
    g2l16(&Bs[(w * 8) * 64],
          &xt[((size_t)(b * Dd + n0 + srow)) * Nn + k0 + skoff]);
    g2l16(&Bs[(64 + w * 8) * 64],
          &xt[((size_t)(b * Dd + n0 + 64 + srow)) * Nn + k0 + skoff]);
    __syncthreads();   // drains vmcnt(0) then barrier
#pragma unroll
    for (int ks = 0; ks < 2; ks++) {
      const int slot = ((ks * 4 + quad) ^ sw) * 8;
      bf16x8 af[4], bf_[2];
#pragma unroll
      for (int mt = 0; mt < 4; mt++)
        af[mt] = *(const bf16x8*)&As[(wm * 64 + mt * 16 + l16) * 64 + slot];
#pragma unroll
      for (int nt = 0; nt < 2; nt++)
        bf_[nt] = *(const bf16x8*)&Bs[(wn * 32 + nt * 16 + l16) * 64 + slot];
#pragma unroll
      for (int mt = 0; mt < 4; mt++)
#pragma unroll
        for (int nt = 0; nt < 2; nt++)
          acc[mt][nt] = __builtin_amdgcn_mfma_f32_16x16x32_bf16(af[mt], bf_[nt], acc[mt][nt], 0, 0, 0);
    }
  }
  // ---- epilogue: y = x + linv[m] * delta ----
  float li[4][4];
#pragma unroll
  for (int mt = 0; mt < 4; mt++)
#pragma unroll
    for (int r = 0; r < 4; r++)
      li[mt][r] = linv_g[(size_t)b * Nn + m0 + wm * 64 + mt * 16 + quad * 4 + r];
#pragma unroll
  for (int mt = 0; mt < 4; mt++)
#pragma unroll
    for (int nt = 0; nt < 2; nt++) {
      const int nn = n0 + wn * 32 + nt * 16 + l16;
#pragma unroll
      for (int r = 0; r < 4; r++) {
        const int m = m0 + wm * 64 + mt * 16 + quad * 4 + r;
        const size_t off = ((size_t)(b * Nn + m)) * Dd + nn;
        y[off] = x[off] + li[mt][r] * acc[mt][nt][r];
      }
    }
}

// ---- ln_k: in-place row-wise LayerNorm over d_out. 1 block (256 thr) per row ----
__global__ __launch_bounds__(256) void ln_k(float* __restrict__ y,
    const float* __restrict__ gamma, const float* __restrict__ beta) {
  __shared__ float rs[4], rq[4];
  const int row = blockIdx.x;
  const int t = threadIdx.x;
  float* p = y + (size_t)row * Dd;
  float4 v = ((const float4*)p)[t];
  float s = v.x + v.y + v.z + v.w;
  float q = v.x * v.x + v.y * v.y + v.z * v.z + v.w * v.w;
#pragma unroll
  for (int off = 32; off; off >>= 1) {
    s += __shfl_xor(s, off);
    q += __shfl_xor(q, off);
  }
  if ((t & 63) == 0) { rs[t >> 6] = s; rq[t >> 6] = q; }
  __syncthreads();
  float S = rs[0] + rs[1] + rs[2] + rs[3];
  float Q2 = rq[0] + rq[1] + rq[2] + rq[3];
  float mu = S * (1.f / Dd);
  float var = Q2 * (1.f / Dd) - mu * mu;
  float rstd = rsqrtf(var + LN_EPS);
  float4 g = ((const float4*)gamma)[t];
  float4 be = ((const float4*)beta)[t];
  v.x = (v.x - mu) * rstd * g.x + be.x;
  v.y = (v.y - mu) * rstd * g.y + be.y;
  v.z = (v.z - mu) * rstd * g.z + be.z;
  v.w = (v.w - mu) * rstd * g.w + be.w;
  ((float4*)p)[t] = v;
}

extern "C" void kernel_launch(void* const* d_in, const int* in_sizes, int n_in,
                              void* d_out, int out_size, void* d_ws, size_t ws_size,
                              hipStream_t stream) {
  const float* x     = (const float*)d_in[0];
  const float* mask  = (const float*)d_in[1];
  const float* U     = (const float*)d_in[2];
  const float* V     = (const float*)d_in[3];
  const float* gamma = (const float*)d_in[4];
  const float* beta  = (const float*)d_in[5];
  float* out = (float*)d_out;
  char* ws = (char*)d_ws;
  // workspace layout (51 MB total)
  u16*   xt   = (u16*)ws;                                        // 16 MB (B,D,N) bf16
  u16*   Qw   = (u16*)(ws + (size_t)(16 << 20));                 // 1 MB
  u16*   Kw   = (u16*)(ws + (size_t)(17 << 20));                 // 1 MB
  u16*   uvt  = (u16*)(ws + (size_t)(18 << 20));                 // 256 KB
  float* qsb  = (float*)(ws + (size_t)(18 << 20) + (256 << 10)); // 32 KB
  float* linv = (float*)(ws + (size_t)(18 << 20) + (288 << 10)); // 32 KB
  u16*   Pw   = (u16*)(ws + (size_t)(19 << 20));                 // 32 MB (B,N,N) bf16

  prep_x       <<<dim3(Nn / 64, Dd / 64, Bb), 256, 0, stream>>>(x, xt);
  prep_small   <<<32 + (Bb * Nn) / 4, 256, 0, stream>>>(U, V, mask, uvt, qsb);
  proj_qk      <<<(Bb * Nn) / 32, 256, 0, stream>>>(x, mask, uvt, Qw, Kw);
  score_softmax<<<Bb * (Nn / 32), 512, 0, stream>>>(Qw, Kw, qsb, Pw, linv);
  pv_gemm      <<<Bb * (Nn / 128) * (Dd / 128), 512, 0, stream>>>(Pw, xt, x, linv, out);
  ln_k         <<<Bb * Nn, 256, 0, stream>>>(out, gamma, beta);
}

// Round 3
// 186.210 us; speedup vs baseline: 1.0630x; 1.0194x over previous
//
#include <hip/hip_runtime.h>

#define Bb 4
#define Nn 2048
#define Dd 1024
#define Rr 64
#define LN_EPS 1e-5f

typedef unsigned short u16;
typedef short bf16x8 __attribute__((ext_vector_type(8)));   // 8 bf16 in 4 VGPRs
typedef float f32x4 __attribute__((ext_vector_type(4)));

__device__ __forceinline__ u16 f2bf(float f) {
  unsigned u = __float_as_uint(f);
  u += 0x7FFFu + ((u >> 16) & 1u);   // RNE
  return (u16)(u >> 16);
}

// async global->LDS, 16 B per lane. LDS dest is wave-uniform base + lane*16.
__device__ __forceinline__ void g2l16(u16* l, const u16* g) {
  __builtin_amdgcn_global_load_lds(
      (const __attribute__((address_space(1))) unsigned int*)g,
      (__attribute__((address_space(3))) unsigned int*)l, 16, 0, 0);
}

// ---- prep_x: x (B,N,D) f32 -> xt (B,D,N) bf16 (d-major, pv_gemm B-operand) ----
// R3: write side packs 2 consecutive n per lane -> u32 stores (256 B/wave-instr).
__global__ __launch_bounds__(256) void prep_x(const float* __restrict__ x,
                                              u16* __restrict__ xt) {
  __shared__ float tile[64][65];
  const int b = blockIdx.z;
  const int n0 = blockIdx.x * 64;
  const int d0 = blockIdx.y * 64;
  const int t = threadIdx.x;
  const int c = t & 63, r4 = t >> 6;
#pragma unroll
  for (int rr = 0; rr < 16; rr++) {
    int row = rr * 4 + r4;
    tile[row][c] = x[(size_t)(b * Nn + n0 + row) * Dd + d0 + c];
  }
  __syncthreads();
  const int c2 = t & 31, r8 = t >> 5;
#pragma unroll
  for (int rr = 0; rr < 8; rr++) {
    int dd = rr * 8 + r8;
    unsigned lo = f2bf(tile[2 * c2][dd]);
    unsigned hi = f2bf(tile[2 * c2 + 1][dd]);
    *(unsigned*)&xt[(size_t)(b * Dd + d0 + dd) * Nn + n0 + 2 * c2] = lo | (hi << 16);
  }
}

// ---- prep_small: fuses prep_uv (blocks 0..31) and qscale (blocks 32..2079) ----
__global__ __launch_bounds__(256) void prep_small(const float* __restrict__ U,
    const float* __restrict__ V, const float* __restrict__ mask,
    u16* __restrict__ uvt, float* __restrict__ qs) {
  if (blockIdx.x < 32) {
    __shared__ float tile[64][65];
    const int which = blockIdx.x >> 4;
    const int d0 = (blockIdx.x & 15) * 64;
    const float* src = which ? V : U;
    const int t = threadIdx.x, c = t & 63, r4 = t >> 6;
#pragma unroll
    for (int rr = 0; rr < 16; rr++) {
      int row = rr * 4 + r4;
      tile[row][c] = src[(size_t)(d0 + row) * Rr + c];
    }
    __syncthreads();
#pragma unroll
    for (int rr = 0; rr < 16; rr++) {
      int r = rr * 4 + r4;
      uvt[(size_t)(which * 64 + r) * Dd + d0 + c] = f2bf(tile[c][r]);
    }
  } else {
    const int row = (blockIdx.x - 32) * 4 + (threadIdx.x >> 6);
    const int lane = threadIdx.x & 63;
    float v = mask[(size_t)row * Rr + lane];
#pragma unroll
    for (int off = 32; off; off >>= 1) v += __shfl_xor(v, off);
    if (lane == 0) qs[row] = rsqrtf(fmaxf(v, 1.0f));
  }
}

// ---- proj_qk: Q = (x@U)*mask, K = (x@V)*mask, bf16 out.
// 32 rows x 128 cols/block (grid 256).
__global__ __launch_bounds__(256) void proj_qk(const float* __restrict__ x,
    const float* __restrict__ mask, const u16* __restrict__ uvt,
    u16* __restrict__ Qo, u16* __restrict__ Ko) {
  const int t = threadIdx.x;
  const int w = t >> 6, l = t & 63, quad = l >> 4, l16 = l & 15;
  const int g0 = blockIdx.x * 32;
  f32x4 acc[2][2];
#pragma unroll
  for (int i = 0; i < 2; i++)
#pragma unroll
    for (int j = 0; j < 2; j++) acc[i][j] = (f32x4){0.f, 0.f, 0.f, 0.f};
  for (int k0 = 0; k0 < Dd; k0 += 32) {
    bf16x8 a[2];
#pragma unroll
    for (int mt = 0; mt < 2; mt++) {
      const float4* px = (const float4*)&x[(size_t)(g0 + mt * 16 + l16) * Dd + k0 + quad * 8];
      float4 x0 = px[0], x1 = px[1];
      bf16x8 av;
      av[0] = (short)f2bf(x0.x); av[1] = (short)f2bf(x0.y);
      av[2] = (short)f2bf(x0.z); av[3] = (short)f2bf(x0.w);
      av[4] = (short)f2bf(x1.x); av[5] = (short)f2bf(x1.y);
      av[6] = (short)f2bf(x1.z); av[7] = (short)f2bf(x1.w);
      a[mt] = av;
    }
    bf16x8 bfr[2];
#pragma unroll
    for (int i = 0; i < 2; i++) {
      int col = (w * 2 + i) * 16 + l16;
      bfr[i] = *(const bf16x8*)&uvt[(size_t)col * Dd + k0 + quad * 8];
    }
#pragma unroll
    for (int mt = 0; mt < 2; mt++)
#pragma unroll
      for (int i = 0; i < 2; i++)
        acc[mt][i] = __builtin_amdgcn_mfma_f32_16x16x32_bf16(a[mt], bfr[i], acc[mt][i], 0, 0, 0);
  }
#pragma unroll
  for (int mt = 0; mt < 2; mt++)
#pragma unroll
    for (int i = 0; i < 2; i++) {
      int col = (w * 2 + i) * 16 + l16;
      int r_ = col & 63;
#pragma unroll
      for (int r = 0; r < 4; r++) {
        int row = g0 + mt * 16 + quad * 4 + r;
        float v = acc[mt][i][r] * mask[(size_t)row * Rr + r_];
        u16 bv = f2bf(v);
        if (col < 64) Qo[(size_t)row * Rr + r_] = bv;
        else          Ko[(size_t)row * Rr + r_] = bv;
      }
    }
}

// ---- score_softmax: block = 32 q-rows x ALL 2048 keys, 8 waves.
// Whole-row softmax once per block. Writes P = exp(v - rowmax) bf16
// (unnormalized) and linv = 1/rowsum.
__global__ __launch_bounds__(512, 2) void score_softmax(
    const u16* __restrict__ Qm, const u16* __restrict__ Km,
    const float* __restrict__ qs, u16* __restrict__ Pw,
    float* __restrict__ linv_g) {
  __shared__ float red[32][8];
  __shared__ float mfin[32];
  const int t = threadIdx.x;
  const int w = t >> 6, l = t & 63, quad = l >> 4, l16 = l & 15;
  const int id = blockIdx.x;
  const int xcd = id & 7;
  const int b = xcd >> 1;
  const int q0 = (((id >> 3) << 1) | (xcd & 1)) * 32;
  bf16x8 qf[2][2];
#pragma unroll
  for (int mt = 0; mt < 2; mt++)
#pragma unroll
    for (int ks = 0; ks < 2; ks++)
      qf[mt][ks] = *(const bf16x8*)&Qm[(size_t)(b * Nn + q0 + mt * 16 + l16) * Rr + ks * 32 + quad * 8];
  f32x4 acc[2][16];
#pragma unroll
  for (int mt = 0; mt < 2; mt++)
#pragma unroll
    for (int nt = 0; nt < 16; nt++) acc[mt][nt] = (f32x4){0.f, 0.f, 0.f, 0.f};
#pragma unroll
  for (int nt = 0; nt < 16; nt++) {
#pragma unroll
    for (int ks = 0; ks < 2; ks++) {
      bf16x8 kf = *(const bf16x8*)&Km[(size_t)(b * Nn + w * 256 + nt * 16 + l16) * Rr + ks * 32 + quad * 8];
#pragma unroll
      for (int mt = 0; mt < 2; mt++)
        acc[mt][nt] = __builtin_amdgcn_mfma_f32_16x16x32_bf16(qf[mt][ks], kf, acc[mt][nt], 0, 0, 0);
    }
  }
  float sc[2][4];
#pragma unroll
  for (int mt = 0; mt < 2; mt++)
#pragma unroll
    for (int r = 0; r < 4; r++)
      sc[mt][r] = qs[(size_t)b * Nn + q0 + mt * 16 + quad * 4 + r];
#pragma unroll
  for (int mt = 0; mt < 2; mt++)
#pragma unroll
    for (int nt = 0; nt < 16; nt++)
#pragma unroll
      for (int r = 0; r < 4; r++) acc[mt][nt][r] *= sc[mt][r];
  float vmax[2][4];
#pragma unroll
  for (int mt = 0; mt < 2; mt++)
#pragma unroll
    for (int r = 0; r < 4; r++) {
      float m = -1e30f;
#pragma unroll
      for (int nt = 0; nt < 16; nt++) m = fmaxf(m, acc[mt][nt][r]);
#pragma unroll
      for (int off = 1; off < 16; off <<= 1) m = fmaxf(m, __shfl_xor(m, off));
      vmax[mt][r] = m;
    }
  if (l16 == 0) {
#pragma unroll
    for (int mt = 0; mt < 2; mt++)
#pragma unroll
      for (int r = 0; r < 4; r++) red[mt * 16 + quad * 4 + r][w] = vmax[mt][r];
  }
  __syncthreads();
  if (t < 32) {
    float m = -1e30f;
#pragma unroll
    for (int i = 0; i < 8; i++) m = fmaxf(m, red[t][i]);
    mfin[t] = m;
  }
  __syncthreads();
  float rowm[2][4], vsum[2][4];
#pragma unroll
  for (int mt = 0; mt < 2; mt++)
#pragma unroll
    for (int r = 0; r < 4; r++) {
      rowm[mt][r] = mfin[mt * 16 + quad * 4 + r];
      vsum[mt][r] = 0.f;
    }
#pragma unroll
  for (int mt = 0; mt < 2; mt++)
#pragma unroll
    for (int nt = 0; nt < 16; nt++)
#pragma unroll
      for (int r = 0; r < 4; r++) {
        float p = __expf(acc[mt][nt][r] - rowm[mt][r]);
        acc[mt][nt][r] = p;
        vsum[mt][r] += p;
      }
#pragma unroll
  for (int mt = 0; mt < 2; mt++)
#pragma unroll
    for (int r = 0; r < 4; r++) {
#pragma unroll
      for (int off = 1; off < 16; off <<= 1) vsum[mt][r] += __shfl_xor(vsum[mt][r], off);
    }
  __syncthreads();   // red[] reuse
  if (l16 == 0) {
#pragma unroll
    for (int mt = 0; mt < 2; mt++)
#pragma unroll
      for (int r = 0; r < 4; r++) red[mt * 16 + quad * 4 + r][w] = vsum[mt][r];
  }
  __syncthreads();
  if (t < 32) {
    float s = 0.f;
#pragma unroll
    for (int i = 0; i < 8; i++) s += red[t][i];
    linv_g[(size_t)b * Nn + q0 + t] = 1.f / s;
  }
#pragma unroll
  for (int mt = 0; mt < 2; mt++)
#pragma unroll
    for (int nt = 0; nt < 16; nt++) {
      const size_t base = ((size_t)(b * Nn + q0 + mt * 16 + quad * 4)) * Nn + w * 256 + nt * 16 + l16;
#pragma unroll
      for (int r = 0; r < 4; r++)
        Pw[base + (size_t)r * Nn] = f2bf(acc[mt][nt][r]);
    }
}

// ---- pv_gemm: delta = P @ X. 128x128 tile, 512 thr (8 waves 2Mx4N), 2-barrier
// structure. R3: BK 64 -> 128. Same staged bytes, same grid 512 (2 blocks/CU;
// LDS 64 KB x2 = 128 <= 160 KB so co-residency unchanged), but HALF the
// vmcnt(0)-drain barriers (16 vs 32) and 2x loads in flight per drain.
// Swizzle (generalized from measured-0-conflict BK=64 pattern): LDS row r
// slot s holds global chunk s^(r&7); staging lane fetches chunk
// (l&15)^(srow&7); frag read slot (ks*4+quad)^(l16&7).
__global__ __launch_bounds__(512, 4) void pv_gemm(
    const u16* __restrict__ Pw, const u16* __restrict__ xt,
    const float* __restrict__ x, const float* __restrict__ linv_g,
    float* __restrict__ y) {
  __shared__ u16 As[128 * 128];   // 32 KB [row m][k-slot] swizzled
  __shared__ u16 Bs[128 * 128];   // 32 KB [col n(d)][k-slot] swizzled
  const int t = threadIdx.x;
  const int w = t >> 6, l = t & 63, quad = l >> 4, l16 = l & 15;
  const int id = blockIdx.x;
  const int xcd = id & 7;
  const int b = xcd >> 1;
  const int nh = xcd & 1;
  const int rest = id >> 3;             // 0..63
  const int m0 = (rest & 15) * 128;     // 16 m-tiles
  const int n0 = (nh * 4 + (rest >> 4)) * 128;  // 8 n-tiles
  const int srow4 = w * 4 + quad;       // staging row within 32-row group (0..31)
  const int sk = ((l & 15) ^ (srow4 & 7)) * 8;  // swizzled global k-chunk (u16)
  const size_t gA = (size_t)(b * Nn + m0 + srow4) * Nn + sk;
  const size_t gB = (size_t)(b * Dd + n0 + srow4) * Nn + sk;
  const int wm = w >> 2, wn = w & 3;    // 2M x 4N wave grid
  const int sw = l16 & 7;
  f32x4 acc[4][2];
#pragma unroll
  for (int i = 0; i < 4; i++)
#pragma unroll
    for (int j = 0; j < 2; j++) acc[i][j] = (f32x4){0.f, 0.f, 0.f, 0.f};
  for (int k0 = 0; k0 < Nn; k0 += 128) {
    __syncthreads();   // previous compute done before LDS overwrite
#pragma unroll
    for (int j = 0; j < 4; j++) {
      g2l16(&As[(j * 32 + w * 4) * 128], &Pw[gA + (size_t)(j * 32) * Nn + k0]);
      g2l16(&Bs[(j * 32 + w * 4) * 128], &xt[gB + (size_t)(j * 32) * Nn + k0]);
    }
    __syncthreads();   // drains vmcnt(0) then barrier
#pragma unroll
    for (int ks = 0; ks < 4; ks++) {
      const int slot = ((ks * 4 + quad) ^ sw) * 8;
      bf16x8 af[4], bf_[2];
#pragma unroll
      for (int mt = 0; mt < 4; mt++)
        af[mt] = *(const bf16x8*)&As[(wm * 64 + mt * 16 + l16) * 128 + slot];
#pragma unroll
      for (int nt = 0; nt < 2; nt++)
        bf_[nt] = *(const bf16x8*)&Bs[(wn * 32 + nt * 16 + l16) * 128 + slot];
#pragma unroll
      for (int mt = 0; mt < 4; mt++)
#pragma unroll
        for (int nt = 0; nt < 2; nt++)
          acc[mt][nt] = __builtin_amdgcn_mfma_f32_16x16x32_bf16(af[mt], bf_[nt], acc[mt][nt], 0, 0, 0);
    }
  }
  // ---- epilogue: y = x + linv[m] * delta ----
  float li[4][4];
#pragma unroll
  for (int mt = 0; mt < 4; mt++)
#pragma unroll
    for (int r = 0; r < 4; r++)
      li[mt][r] = linv_g[(size_t)b * Nn + m0 + wm * 64 + mt * 16 + quad * 4 + r];
#pragma unroll
  for (int mt = 0; mt < 4; mt++)
#pragma unroll
    for (int nt = 0; nt < 2; nt++) {
      const int nn = n0 + wn * 32 + nt * 16 + l16;
#pragma unroll
      for (int r = 0; r < 4; r++) {
        const int m = m0 + wm * 64 + mt * 16 + quad * 4 + r;
        const size_t off = ((size_t)(b * Nn + m)) * Dd + nn;
        y[off] = x[off] + li[mt][r] * acc[mt][nt][r];
      }
    }
}

// ---- ln_k: in-place row-wise LayerNorm over d_out. 1 block (256 thr) per row ----
__global__ __launch_bounds__(256) void ln_k(float* __restrict__ y,
    const float* __restrict__ gamma, const float* __restrict__ beta) {
  __shared__ float rs[4], rq[4];
  const int row = blockIdx.x;
  const int t = threadIdx.x;
  float* p = y + (size_t)row * Dd;
  float4 v = ((const float4*)p)[t];
  float s = v.x + v.y + v.z + v.w;
  float q = v.x * v.x + v.y * v.y + v.z * v.z + v.w * v.w;
#pragma unroll
  for (int off = 32; off; off >>= 1) {
    s += __shfl_xor(s, off);
    q += __shfl_xor(q, off);
  }
  if ((t & 63) == 0) { rs[t >> 6] = s; rq[t >> 6] = q; }
  __syncthreads();
  float S = rs[0] + rs[1] + rs[2] + rs[3];
  float Q2 = rq[0] + rq[1] + rq[2] + rq[3];
  float mu = S * (1.f / Dd);
  float var = Q2 * (1.f / Dd) - mu * mu;
  float rstd = rsqrtf(var + LN_EPS);
  float4 g = ((const float4*)gamma)[t];
  float4 be = ((const float4*)beta)[t];
  v.x = (v.x - mu) * rstd * g.x + be.x;
  v.y = (v.y - mu) * rstd * g.y + be.y;
  v.z = (v.z - mu) * rstd * g.z + be.z;
  v.w = (v.w - mu) * rstd * g.w + be.w;
  ((float4*)p)[t] = v;
}

extern "C" void kernel_launch(void* const* d_in, const int* in_sizes, int n_in,
                              void* d_out, int out_size, void* d_ws, size_t ws_size,
                              hipStream_t stream) {
  const float* x     = (const float*)d_in[0];
  const float* mask  = (const float*)d_in[1];
  const float* U     = (const float*)d_in[2];
  const float* V     = (const float*)d_in[3];
  const float* gamma = (const float*)d_in[4];
  const float* beta  = (const float*)d_in[5];
  float* out = (float*)d_out;
  char* ws = (char*)d_ws;
  // workspace layout (51 MB total)
  u16*   xt   = (u16*)ws;                                        // 16 MB (B,D,N) bf16
  u16*   Qw   = (u16*)(ws + (size_t)(16 << 20));                 // 1 MB
  u16*   Kw   = (u16*)(ws + (size_t)(17 << 20));                 // 1 MB
  u16*   uvt  = (u16*)(ws + (size_t)(18 << 20));                 // 256 KB
  float* qsb  = (float*)(ws + (size_t)(18 << 20) + (256 << 10)); // 32 KB
  float* linv = (float*)(ws + (size_t)(18 << 20) + (288 << 10)); // 32 KB
  u16*   Pw   = (u16*)(ws + (size_t)(19 << 20));                 // 32 MB (B,N,N) bf16

  prep_x       <<<dim3(Nn / 64, Dd / 64, Bb), 256, 0, stream>>>(x, xt);
  prep_small   <<<32 + (Bb * Nn) / 4, 256, 0, stream>>>(U, V, mask, uvt, qsb);
  proj_qk      <<<(Bb * Nn) / 32, 256, 0, stream>>>(x, mask, uvt, Qw, Kw);
  score_softmax<<<Bb * (Nn / 32), 512, 0, stream>>>(Qw, Kw, qsb, Pw, linv);
  pv_gemm      <<<Bb * (Nn / 128) * (Dd / 128), 512, 0, stream>>>(Pw, xt, x, linv, out);
  ln_k         <<<Bb * Nn, 256, 0, stream>>>(out, gamma, beta);
}